// Round 1
// baseline (1991.661 us; speedup 1.0000x reference)
//
#include <hip/hip_runtime.h>

#define BB  1024
#define TT  1000
#define DD  6
#define HN  32
#define HHN 15

// broadcast value from lane l (uniform l) -> lands in SGPR
__device__ __forceinline__ float bcastf(float v, int l) {
    return __uint_as_float(__builtin_amdgcn_readlane(__float_as_uint(v), l));
}

// tanh(x) = 1 - 2/(exp(2x)+1); exact saturation at +/-inf, rel err ~1e-6
__device__ __forceinline__ float tanh_fast(float x) {
    float e = __expf(2.0f * x);
    return fmaf(-2.0f, __builtin_amdgcn_rcpf(e + 1.0f), 1.0f);
}

extern "C" __global__ void __launch_bounds__(64)
cde_kernel(const float* __restrict__ coeffs,
           const float* __restrict__ W0, const float* __restrict__ b0,
           const float* __restrict__ W1, const float* __restrict__ b1,
           const float* __restrict__ W2, const float* __restrict__ b2,
           const float* __restrict__ W3, const float* __restrict__ b3,
           const float* __restrict__ W4, const float* __restrict__ b4,
           const float* __restrict__ Wf, const float* __restrict__ bf,
           float* __restrict__ out)
{
    const int b    = blockIdx.x;
    const int lane = threadIdx.x;            // 0..63, one wave per block
    const float* cb = coeffs + (size_t)b * (TT * DD);

    // ---- per-lane weight columns (registers) ----
    // lanes 0..14 own output neuron i of layers 1..3
    const int i = (lane < HHN) ? lane : 0;
    float w1[HN], w2[HHN], w3[HHN];
    #pragma unroll
    for (int k = 0; k < HN; ++k)  w1[k] = W1[k * HHN + i];
    #pragma unroll
    for (int k = 0; k < HHN; ++k) w2[k] = W2[k * HHN + i];
    #pragma unroll
    for (int k = 0; k < HHN; ++k) w3[k] = W3[k * HHN + i];
    const float bias1 = b1[i], bias2 = b2[i], bias3 = b3[i];

    // layer 4: each lane owns 3 of the 192 output columns: c = 3*lane + q
    const int c0 = 3 * lane;
    float w4[3][HHN], bias4[3];
    #pragma unroll
    for (int q = 0; q < 3; ++q) {
        bias4[q] = b4[c0 + q];
        #pragma unroll
        for (int k = 0; k < HHN; ++k) w4[q][k] = W4[k * (HN * DD) + c0 + q];
    }

    // ---- h0 = coeffs[:,0,:] @ W0 + b0, distributed: lane j<32 holds h[j] ----
    const int j = (lane < HN) ? lane : 0;
    float x0[DD];
    #pragma unroll
    for (int d = 0; d < DD; ++d) x0[d] = cb[d];
    float h = b0[j];
    #pragma unroll
    for (int d = 0; d < DD; ++d) h = fmaf(x0[d], W0[d * HN + j], h);

    float xc[DD];
    #pragma unroll
    for (int d = 0; d < DD; ++d) xc[d] = x0[d];

    #pragma unroll 1
    for (int t = 0; t < TT - 1; ++t) {
        // next sample (uniform loads; latency hidden under the step's compute)
        float xn[DD];
        #pragma unroll
        for (int d = 0; d < DD; ++d) xn[d] = cb[(t + 1) * DD + d];
        float dx[DD];
        #pragma unroll
        for (int d = 0; d < DD; ++d) dx[d] = xn[d] - xc[d];
        // lane's 3 columns c=3L+q map to d=(3L+q)%6: even lane -> d=q, odd -> d=3+q
        float dxl[3];
        #pragma unroll
        for (int q = 0; q < 3; ++q) dxl[q] = (lane & 1) ? dx[3 + q] : dx[q];

        // one vector-field eval: input y distributed (lane j holds y[j]),
        // returns k = f(y) . dx distributed the same way
        auto evalg = [&](float vy) -> float {
            // layer 1: z1[i] = relu(sum_k y[k] W1[k,i] + b1[i]), on lanes 0..14
            float z1a = 0.f, z1b = 0.f;
            #pragma unroll
            for (int k = 0; k < HN; k += 2) {
                z1a = fmaf(bcastf(vy, k),     w1[k],     z1a);
                z1b = fmaf(bcastf(vy, k + 1), w1[k + 1], z1b);
            }
            float z1 = fmaxf(bias1 + z1a + z1b, 0.f);

            // layer 2
            float z2a = 0.f, z2b = 0.f;
            #pragma unroll
            for (int k = 0; k < HHN - 1; k += 2) {
                z2a = fmaf(bcastf(z1, k),     w2[k],     z2a);
                z2b = fmaf(bcastf(z1, k + 1), w2[k + 1], z2b);
            }
            z2a = fmaf(bcastf(z1, HHN - 1), w2[HHN - 1], z2a);
            float z2 = fmaxf(bias2 + z2a + z2b, 0.f);

            // layer 3
            float z3a = 0.f, z3b = 0.f;
            #pragma unroll
            for (int k = 0; k < HHN - 1; k += 2) {
                z3a = fmaf(bcastf(z2, k),     w3[k],     z3a);
                z3b = fmaf(bcastf(z2, k + 1), w3[k + 1], z3b);
            }
            z3a = fmaf(bcastf(z2, HHN - 1), w3[HHN - 1], z3a);
            float z3 = fmaxf(bias3 + z3a + z3b, 0.f);

            // broadcast z3 to all lanes (SGPRs)
            float z3v[HHN];
            #pragma unroll
            for (int k = 0; k < HHN; ++k) z3v[k] = bcastf(z3, k);

            // layer 4 + tanh + dot with dx: all 64 lanes, 3 columns each
            float partial = 0.f;
            #pragma unroll
            for (int q = 0; q < 3; ++q) {
                float s = bias4[q];
                #pragma unroll
                for (int k = 0; k < HHN; ++k) s = fmaf(z3v[k], w4[q][k], s);
                partial = fmaf(tanh_fast(s), dxl[q], partial);
            }
            // g[hidx] = partial(lane 2*hidx) + partial(lane 2*hidx+1)
            partial += __shfl_xor(partial, 1);
            // redistribute: lane j wants g[j], which lives on lane 2j
            return __shfl(partial, 2 * lane);
        };

        const float k1 = evalg(h);
        const float k2 = evalg(fmaf(0.5f, k1, h));
        const float k3 = evalg(fmaf(0.5f, k2, h));
        const float k4 = evalg(h + k3);
        h = h + (k1 + 2.f * k2 + 2.f * k3 + k4) * (1.0f / 6.0f);

        #pragma unroll
        for (int d = 0; d < DD; ++d) xc[d] = xn[d];
    }

    // ---- out[b] = sum_j h[j] * Wf[j] + bf[0] ----
    float p = (lane < HN) ? h * Wf[j] : 0.f;
    #pragma unroll
    for (int off = 32; off > 0; off >>= 1) p += __shfl_xor(p, off);
    if (lane == 0) out[b] = p + bf[0];
}

extern "C" void kernel_launch(void* const* d_in, const int* in_sizes, int n_in,
                              void* d_out, int out_size, void* d_ws, size_t ws_size,
                              hipStream_t stream) {
    const float* coeffs = (const float*)d_in[0];
    const float* W0 = (const float*)d_in[1];
    const float* b0 = (const float*)d_in[2];
    const float* W1 = (const float*)d_in[3];
    const float* b1 = (const float*)d_in[4];
    const float* W2 = (const float*)d_in[5];
    const float* b2 = (const float*)d_in[6];
    const float* W3 = (const float*)d_in[7];
    const float* b3 = (const float*)d_in[8];
    const float* W4 = (const float*)d_in[9];
    const float* b4 = (const float*)d_in[10];
    const float* Wf = (const float*)d_in[11];
    const float* bf = (const float*)d_in[12];
    float* out = (float*)d_out;

    hipLaunchKernelGGL(cde_kernel, dim3(BB), dim3(64), 0, stream,
                       coeffs, W0, b0, W1, b1, W2, b2, W3, b3, W4, b4, Wf, bf, out);
}

// Round 2
// 1643.698 us; speedup vs baseline: 1.2117x; 1.2117x over previous
//
#include <hip/hip_runtime.h>

#define BB  1024
#define TT  1000
#define DD  6
#define HN  32
#define HHN 15

#define PIN(x) asm volatile("" : "+v"(x))

// broadcast from uniform lane -> SGPR
__device__ __forceinline__ float bcastf(float v, int l) {
    return __uint_as_float(__builtin_amdgcn_readlane(__float_as_uint(v), l));
}
// per-lane gather: result = src[byteaddr/4]
__device__ __forceinline__ float bpermf(int byteaddr, float v) {
    return __int_as_float(__builtin_amdgcn_ds_bpermute(byteaddr, __float_as_int(v)));
}
// butterfly add within quad via DPP quad_perm
template<int CTRL>
__device__ __forceinline__ float qxadd(float v) {
    int t = __builtin_amdgcn_update_dpp(0, __float_as_int(v), CTRL, 0xF, 0xF, true);
    return v + __int_as_float(t);
}
// tanh(x) = 1 - 2/(exp2(2*log2e*x)+1); exact saturation, rel err ~1e-6
__device__ __forceinline__ float tanh_fast(float x) {
    float e = __builtin_amdgcn_exp2f(x * 2.885390081777927f);
    return fmaf(-2.0f, __builtin_amdgcn_rcpf(e + 1.0f), 1.0f);
}

extern "C" __global__ void __launch_bounds__(64, 1)
cde_kernel(const float* __restrict__ coeffs,
           const float* __restrict__ W0, const float* __restrict__ b0,
           const float* __restrict__ W1, const float* __restrict__ b1,
           const float* __restrict__ W2, const float* __restrict__ b2,
           const float* __restrict__ W3, const float* __restrict__ b3,
           const float* __restrict__ W4, const float* __restrict__ b4,
           const float* __restrict__ Wf, const float* __restrict__ bf,
           float* __restrict__ out)
{
    const int b = blockIdx.x;
    const int L = threadIdx.x;              // one wave per block
    const float* cb = coeffs + (size_t)b * (TT * DD);

    // stage this block's coeffs in LDS (24 KB)
    __shared__ float xs[TT * DD];
    for (int idx = L; idx < TT * DD; idx += 64) xs[idx] = cb[idx];

    // ---- lane roles ----
    const int quad = L >> 2;                // 0..15 (neuron for layers 1-3, <15 valid)
    const int p    = L & 3;                 // k-chunk within neuron
    const int iq   = (quad < 15) ? quad : 14;
    const int hb   = L & 31;                // owned h index (half-replicated)
    const int hi   = L >> 5;                // which half

    // ---- persistent weights in VGPRs (pinned) ----
    float w1l[8];                           // layer1: k = 8p+m
    #pragma unroll
    for (int m = 0; m < 8; ++m) { w1l[m] = W1[(8 * p + m) * HHN + iq]; PIN(w1l[m]); }

    float w2l[4], w3l[4];                   // layers2/3: k = 4p+m (clamped; z[15]=0 masks)
    #pragma unroll
    for (int m = 0; m < 4; ++m) {
        int kk = 4 * p + m; if (kk > 14) kk = 14;
        w2l[m] = W2[kk * HHN + iq]; PIN(w2l[m]);
        w3l[m] = W3[kk * HHN + iq]; PIN(w3l[m]);
    }
    // biases: -1e30 on quad 15 -> relu gives exactly 0 there
    float bias1 = (quad < 15) ? b1[iq] : -1e30f; PIN(bias1);
    float bias2 = (quad < 15) ? b2[iq] : -1e30f; PIN(bias2);
    float bias3 = (quad < 15) ? b3[iq] : -1e30f; PIN(bias3);

    // layer4: lane owns cols c = 6*hb + 3*hi + q  (pair (L, L^32) covers h=hb)
    float w4l[3][HHN], bias4[3];
    #pragma unroll
    for (int q = 0; q < 3; ++q) {
        const int c = hb * (HN * DD / HN * 1) * 0 + hb * DD + hi * 3 + q; // c = hb*6 + hi*3 + q
        bias4[q] = b4[c]; PIN(bias4[q]);
        #pragma unroll
        for (int k = 0; k < HHN; ++k) { w4l[q][k] = W4[k * (HN * DD) + c]; PIN(w4l[q][k]); }
    }

    // gather byte-addresses (loop-invariant)
    const int a1 = 32 * p;                  // layer1: +4m  -> lane 8p+m
    const int a2 = 64 * p;                  // layers2/3: +16m -> lane 4*(4p+m)

    __syncthreads();

    // ---- h0 = x0 @ W0 + b0, half-replicated: lane holds h[hb] ----
    float h = b0[hb];
    #pragma unroll
    for (int d = 0; d < DD; ++d) h = fmaf(xs[d], W0[d * HN + hb], h);

    float xA[DD], xB[DD];
    #pragma unroll
    for (int d = 0; d < DD; ++d) { xA[d] = xs[d]; xB[d] = xs[DD + d]; }

    #pragma unroll 1
    for (int t = 0; t < TT - 1; ++t) {
        float dx[DD];
        #pragma unroll
        for (int d = 0; d < DD; ++d) dx[d] = xB[d] - xA[d];
        const float dx0 = hi ? dx[3] : dx[0];
        const float dx1 = hi ? dx[4] : dx[1];
        const float dx2 = hi ? dx[5] : dx[2];

        // prefetch x[t+2] (consumed next iteration)
        float xN[DD];
        const int tn = (t + 2 < TT) ? (t + 2) : (TT - 1);
        #pragma unroll
        for (int d = 0; d < DD; ++d) xN[d] = xs[tn * DD + d];

        // one vector-field eval contracted with dx; input/output half-replicated
        auto evalg = [&](float y) -> float {
            // layer 1: 480 MACs over 60 lanes
            float sa = 0.f, sb = 0.f;
            #pragma unroll
            for (int m = 0; m < 8; m += 2) {
                float ya = bpermf(a1 + 4 * m,     y);
                float yb = bpermf(a1 + 4 * m + 4, y);
                sa = fmaf(ya, w1l[m],     sa);
                sb = fmaf(yb, w1l[m + 1], sb);
            }
            float s1 = sa + sb;
            s1 = qxadd<0xB1>(s1); s1 = qxadd<0x4E>(s1);
            const float z1 = fmaxf(s1 + bias1, 0.f);

            // layer 2
            float s2a = 0.f, s2b = 0.f;
            #pragma unroll
            for (int m = 0; m < 4; m += 2) {
                float za = bpermf(a2 + 16 * m,      z1);
                float zb = bpermf(a2 + 16 * m + 16, z1);
                s2a = fmaf(za, w2l[m],     s2a);
                s2b = fmaf(zb, w2l[m + 1], s2b);
            }
            float s2 = s2a + s2b;
            s2 = qxadd<0xB1>(s2); s2 = qxadd<0x4E>(s2);
            const float z2 = fmaxf(s2 + bias2, 0.f);

            // layer 3
            float s3a = 0.f, s3b = 0.f;
            #pragma unroll
            for (int m = 0; m < 4; m += 2) {
                float za = bpermf(a2 + 16 * m,      z2);
                float zb = bpermf(a2 + 16 * m + 16, z2);
                s3a = fmaf(za, w3l[m],     s3a);
                s3b = fmaf(zb, w3l[m + 1], s3b);
            }
            float s3 = s3a + s3b;
            s3 = qxadd<0xB1>(s3); s3 = qxadd<0x4E>(s3);
            const float z3 = fmaxf(s3 + bias3, 0.f);

            // broadcast z3 (lives on lane 4k) to SGPRs
            float z3v[HHN];
            #pragma unroll
            for (int k = 0; k < HHN; ++k) z3v[k] = bcastf(z3, 4 * k);

            // layer 4 + tanh + dot(dx): all 64 lanes, 3 cols each
            float partial = 0.f;
            #pragma unroll
            for (int q = 0; q < 3; ++q) {
                float s = bias4[q];
                #pragma unroll
                for (int k = 0; k < HHN; ++k) s = fmaf(z3v[k], w4l[q][k], s);
                const float dq = (q == 0) ? dx0 : ((q == 1) ? dx1 : dx2);
                partial = fmaf(tanh_fast(s), dq, partial);
            }
            // g[hb] = partial(L) + partial(L^32), replicated to both halves
            return partial + __shfl_xor(partial, 32);
        };

        const float k1 = evalg(h);
        const float k2 = evalg(fmaf(0.5f, k1, h));
        const float k3 = evalg(fmaf(0.5f, k2, h));
        const float k4 = evalg(h + k3);
        h = fmaf(fmaf(2.f, k2 + k3, k1 + k4), 1.f / 6.f, h);

        #pragma unroll
        for (int d = 0; d < DD; ++d) { xA[d] = xB[d]; xB[d] = xN[d]; }
    }

    // ---- out[b] = h . Wf + bf (each product appears on 2 lanes -> *0.5) ----
    float pz = h * Wf[hb];
    #pragma unroll
    for (int off = 32; off > 0; off >>= 1) pz += __shfl_xor(pz, off);
    if (L == 0) out[b] = fmaf(pz, 0.5f, bf[0]);
}

extern "C" void kernel_launch(void* const* d_in, const int* in_sizes, int n_in,
                              void* d_out, int out_size, void* d_ws, size_t ws_size,
                              hipStream_t stream) {
    const float* coeffs = (const float*)d_in[0];
    const float* W0 = (const float*)d_in[1];
    const float* b0 = (const float*)d_in[2];
    const float* W1 = (const float*)d_in[3];
    const float* b1 = (const float*)d_in[4];
    const float* W2 = (const float*)d_in[5];
    const float* b2 = (const float*)d_in[6];
    const float* W3 = (const float*)d_in[7];
    const float* b3 = (const float*)d_in[8];
    const float* W4 = (const float*)d_in[9];
    const float* b4 = (const float*)d_in[10];
    const float* Wf = (const float*)d_in[11];
    const float* bf = (const float*)d_in[12];
    float* out = (float*)d_out;

    hipLaunchKernelGGL(cde_kernel, dim3(BB), dim3(64), 0, stream,
                       coeffs, W0, b0, W1, b1, W2, b2, W3, b3, W4, b4, Wf, bf, out);
}